// Round 1
// baseline (669.034 us; speedup 1.0000x reference)
//
#include <hip/hip_runtime.h>

#define CIN   256
#define COUT  512
#define HW    1024     // H*W = 32*32
#define ITERS 20

typedef __attribute__((ext_vector_type(8))) short bf16x8;
typedef __attribute__((ext_vector_type(4))) float f32x4;

__device__ __forceinline__ unsigned short f2b(float x) {
  unsigned b = __builtin_bit_cast(unsigned, x);
  unsigned r = (b + 0x7FFFu + ((b >> 16) & 1u)) >> 16;   // RNE
  return (unsigned short)r;
}
__device__ __forceinline__ float b2f(unsigned short u) {
  return __builtin_bit_cast(float, (unsigned)u << 16);
}

// Pre-swizzle weight into MFMA B-fragment layouts (bf16), once per launch.
// W1: GEMM1 B[k=j][n=c] = w[j*CIN+c], frags [ct:16][kt:16][lane:64][i:8]
// W2: GEMM2 B[k=c][n=j] = w[j*CIN+c], frags [jt:32][kt:8][lane:64][i:8]
__global__ __launch_bounds__(256) void prep_weights(const float* __restrict__ w,
                                                    unsigned short* __restrict__ w1,
                                                    unsigned short* __restrict__ w2) {
  int f = blockIdx.x * 256 + threadIdx.x;   // [0, 131072)
  {
    int i = f & 7, lane = (f >> 3) & 63, kt = (f >> 9) & 15, ct = f >> 13;
    int n = ct * 16 + (lane & 15);
    int k = kt * 32 + (lane >> 4) * 8 + i;
    w1[f] = f2b(w[k * CIN + n]);
  }
  {
    int i = f & 7, lane = (f >> 3) & 63, kt = (f >> 9) & 7, jt = f >> 12;
    int n = jt * 16 + (lane & 15);
    int k = kt * 32 + (lane >> 4) * 8 + i;
    w2[f] = f2b(w[n * CIN + k]);
  }
}

// Fused NNMF: 1 WG = 32 pixels, all 20 iterations on-chip.
// h state: fp32 in registers (GEMM2 C-layout). bf16 copies in LDS feed MFMA.
__global__ __launch_bounds__(256, 2) void nnmf_kernel(const float* __restrict__ xin,
                                                      const unsigned short* __restrict__ w1,
                                                      const unsigned short* __restrict__ w2,
                                                      float* __restrict__ out) {
  // 32KB + 16KB + 16KB = 65536 B exactly
  __shared__ __align__(16) unsigned short hA[2 * 16 * 64 * 8]; // GEMM1 A-frags (m-tile, k-tile)
  __shared__ __align__(16) unsigned short xF[2 * 8 * 64 * 8];  // x, GEMM2 A-frag layout
  __shared__ __align__(16) unsigned short yF[2 * 8 * 64 * 8];  // y, GEMM2 A-frag layout (+sum alias)

  const int tid  = threadIdx.x;
  const int wave = tid >> 6;
  const int lane = tid & 63;
  const int quad = lane >> 4;
  const int col  = lane & 15;

  const int wg     = blockIdx.x;
  const int bb     = wg >> 5;              // batch image
  const int hwbase = (wg & 31) * 32;       // 32 consecutive pixels in one image
  const float* xbase = xin + (size_t)bb * (CIN * HW) + hwbase;

  // ---- stage x tile (bf16, A-frag layout) ; init hA = bf16(1/512) (exact) ----
  {
    int m  = tid & 31;
    int cb = tid >> 5;
#pragma unroll
    for (int g = 0; g < 32; ++g) {
      int c = cb + (g << 3);
      float xv = xbase[c * HW + m];
      int idx = (((m >> 4) * 8 + (c >> 5)) * 64 + ((m & 15) | (((c >> 3) & 3) << 4))) * 8 + (c & 7);
      xF[idx] = f2b(xv);
    }
    unsigned* h32 = (unsigned*)hA;
#pragma unroll
    for (int g = 0; g < 32; ++g) h32[tid + (g << 8)] = 0x3B003B00u;  // two bf16(2^-9)
  }
  __syncthreads();

  // persistent fp32 h, GEMM2-C layout: m = mt*16+quad*4+r, j = (wave*8+n)*16+col
  f32x4 hreg[2][8];
#pragma unroll
  for (int mt = 0; mt < 2; ++mt)
#pragma unroll
    for (int n = 0; n < 8; ++n)
#pragma unroll
      for (int r = 0; r < 4; ++r) hreg[mt][n][r] = 1.0f / 512.0f;

  for (int it = 0; it < ITERS; ++it) {
    // ===== GEMM1: rec[m][c] = sum_j h[m][j] W[j][c] ; wave owns ct = wave*4+n =====
    f32x4 acc1[2][4];
#pragma unroll
    for (int mt = 0; mt < 2; ++mt)
#pragma unroll
      for (int n = 0; n < 4; ++n)
#pragma unroll
        for (int r = 0; r < 4; ++r) acc1[mt][n][r] = 0.0f;

#pragma unroll 2
    for (int kt = 0; kt < 16; ++kt) {
      bf16x8 a0 = *(const bf16x8*)(hA + ((kt) * 64 + lane) * 8);
      bf16x8 a1 = *(const bf16x8*)(hA + ((16 + kt) * 64 + lane) * 8);
#pragma unroll
      for (int n = 0; n < 4; ++n) {
        int ct = (wave << 2) + n;
        bf16x8 b = *(const bf16x8*)(w1 + (((ct << 4) + kt) * 64 + lane) * 8);
        acc1[0][n] = __builtin_amdgcn_mfma_f32_16x16x32_bf16(a0, b, acc1[0][n], 0, 0, 0);
        acc1[1][n] = __builtin_amdgcn_mfma_f32_16x16x32_bf16(a1, b, acc1[1][n], 0, 0, 0);
      }
    }

    // ===== y = x / (rec + 1e-20) -> yF (bf16, A-frag layout) =====
#pragma unroll
    for (int mt = 0; mt < 2; ++mt)
#pragma unroll
      for (int n = 0; n < 4; ++n) {
        int c = ((((wave << 2) + n) << 4) + col);
        int fragbase = ((mt * 8 + (c >> 5)) * 64) * 8;
        int lanehi = ((c >> 3) & 3) << 4;
        int ilow = c & 7;
#pragma unroll
        for (int r = 0; r < 4; ++r) {
          int m = (mt << 4) + (quad << 2) + r;
          int idx = fragbase + ((m & 15) | lanehi) * 8 + ilow;
          float yv = b2f(xF[idx]) * __builtin_amdgcn_rcpf(acc1[mt][n][r] + 1e-20f);
          yF[idx] = f2b(yv);
        }
      }
    __syncthreads();  // yF complete

    // ===== GEMM2: t[m][j] = sum_c y[m][c] W[j][c] ; wave owns jt = wave*8+n =====
    f32x4 acc2[2][8];
#pragma unroll
    for (int mt = 0; mt < 2; ++mt)
#pragma unroll
      for (int n = 0; n < 8; ++n)
#pragma unroll
        for (int r = 0; r < 4; ++r) acc2[mt][n][r] = 0.0f;

#pragma unroll 2
    for (int kt = 0; kt < 8; ++kt) {
      bf16x8 a0 = *(const bf16x8*)(yF + ((kt) * 64 + lane) * 8);
      bf16x8 a1 = *(const bf16x8*)(yF + ((8 + kt) * 64 + lane) * 8);
#pragma unroll
      for (int n = 0; n < 8; ++n) {
        int jt = (wave << 3) + n;
        bf16x8 b = *(const bf16x8*)(w2 + (((jt << 3) + kt) * 64 + lane) * 8);
        acc2[0][n] = __builtin_amdgcn_mfma_f32_16x16x32_bf16(a0, b, acc2[0][n], 0, 0, 0);
        acc2[1][n] = __builtin_amdgcn_mfma_f32_16x16x32_bf16(a1, b, acc2[1][n], 0, 0, 0);
      }
    }

    // ===== h *= t (fp32), row-sum, normalize =====
    float psum[8];
#pragma unroll
    for (int k = 0; k < 8; ++k) psum[k] = 0.0f;
#pragma unroll
    for (int mt = 0; mt < 2; ++mt)
#pragma unroll
      for (int n = 0; n < 8; ++n)
#pragma unroll
        for (int r = 0; r < 4; ++r) {
          float hn = hreg[mt][n][r] * acc2[mt][n][r];
          hreg[mt][n][r] = hn;
          psum[mt * 4 + r] += hn;
        }
    // butterfly over the 16 col-lanes of each quad
#pragma unroll
    for (int mask = 1; mask < 16; mask <<= 1)
#pragma unroll
      for (int k = 0; k < 8; ++k) psum[k] += __shfl_xor(psum[k], mask, 64);

    __syncthreads();  // all waves done reading yF -> safe to alias
    float* red = (float*)yF;   // [m:32][wave:4]
    if (col == 0) {
#pragma unroll
      for (int mt = 0; mt < 2; ++mt)
#pragma unroll
        for (int r = 0; r < 4; ++r) {
          int m = (mt << 4) + (quad << 2) + r;
          red[m * 4 + wave] = psum[mt * 4 + r];
        }
    }
    __syncthreads();

#pragma unroll
    for (int mt = 0; mt < 2; ++mt)
#pragma unroll
      for (int r = 0; r < 4; ++r) {
        int m = (mt << 4) + (quad << 2) + r;
        f32x4 p = *(const f32x4*)(red + m * 4);
        float inv = __builtin_amdgcn_rcpf(p[0] + p[1] + p[2] + p[3] + 1e-19f);
#pragma unroll
        for (int n = 0; n < 8; ++n) hreg[mt][n][r] *= inv;
      }

    if (it < ITERS - 1) {
      // bf16 copy of h into hA (GEMM1 A-frag layout) for next iteration
#pragma unroll
      for (int mt = 0; mt < 2; ++mt)
#pragma unroll
        for (int n = 0; n < 8; ++n) {
          int j = ((((wave << 3) + n) << 4) + col);
          int base = ((mt * 16 + (j >> 5)) * 64) * 8;
          int lanehi = ((j >> 3) & 3) << 4;
          int ilow = j & 7;
#pragma unroll
          for (int r = 0; r < 4; ++r) {
            int m = (mt << 4) + (quad << 2) + r;
            hA[base + ((m & 15) | lanehi) * 8 + ilow] = f2b(hreg[mt][n][r]);
          }
        }
    } else {
      // final store, fp32: out[b][j][hw] ; 4 consecutive m per lane -> dwordx4
      float* obase = out + (size_t)bb * (COUT * HW) + hwbase;
#pragma unroll
      for (int mt = 0; mt < 2; ++mt)
#pragma unroll
        for (int n = 0; n < 8; ++n) {
          int j = ((((wave << 3) + n) << 4) + col);
          *(f32x4*)(obase + j * HW + (mt << 4) + (quad << 2)) = hreg[mt][n];
        }
    }
    __syncthreads();
  }
}

extern "C" void kernel_launch(void* const* d_in, const int* in_sizes, int n_in,
                              void* d_out, int out_size, void* d_ws, size_t ws_size,
                              hipStream_t stream) {
  const float* x = (const float*)d_in[0];   // [32,256,32,32]
  const float* w = (const float*)d_in[1];   // [512,256]
  unsigned short* w1 = (unsigned short*)d_ws;          // 256 KB
  unsigned short* w2 = w1 + COUT * CIN;                // 256 KB
  float* out = (float*)d_out;

  prep_weights<<<dim3(512), dim3(256), 0, stream>>>(w, w1, w2);
  nnmf_kernel<<<dim3(32768 / 32), dim3(256), 0, stream>>>(x, w1, w2, out);
}